// Round 5
// baseline (112.033 us; speedup 1.0000x reference)
//
#include <hip/hip_runtime.h>

#define N 8192
#define FIN 512
#define FOUT 256
#define ALPHA 0.2f
#define ROWS_PER_BLOCK 4

// native clang vector types — required by __builtin_nontemporal_load/store
typedef int   iv4 __attribute__((ext_vector_type(4)));
typedef float fv4 __attribute__((ext_vector_type(4)));

// ---------------------------------------------------------------------------
// Kernel A: u1 = W @ a[:256], u2 = W @ a[256:]   (512-length vectors)
// One wave per output k: 64 lanes x fv4 = the full contiguous 256-float row
// of W (coalesced), dot with a, shuffle-reduce. 512 waves total.
// ---------------------------------------------------------------------------
__global__ __launch_bounds__(256) void gat_compute_u(const float* __restrict__ W,
                                                     const float* __restrict__ a,
                                                     float* __restrict__ u1,
                                                     float* __restrict__ u2) {
    int gtid = blockIdx.x * blockDim.x + threadIdx.x;
    int k    = gtid >> 6;
    int lane = gtid & 63;
    if (k >= FIN) return;
    fv4 wv  = *(const fv4*)(W + (size_t)k * FOUT + lane * 4);
    fv4 a1v = *(const fv4*)(a + lane * 4);
    fv4 a2v = *(const fv4*)(a + FOUT + lane * 4);
    float acc1 = wv.x * a1v.x + wv.y * a1v.y + wv.z * a1v.z + wv.w * a1v.w;
    float acc2 = wv.x * a2v.x + wv.y * a2v.y + wv.z * a2v.z + wv.w * a2v.w;
    #pragma unroll
    for (int off = 32; off > 0; off >>= 1) {
        acc1 += __shfl_xor(acc1, off);
        acc2 += __shfl_xor(acc2, off);
    }
    if (lane == 0) {
        u1[k] = acc1;
        u2[k] = acc2;
    }
}

// ---------------------------------------------------------------------------
// Kernel B: s1[i] = dot(h[i,:], u1), s2[i] = dot(h[i,:], u2)
// One wave per row; fv4 loads; reads h once (16 MB).
// ---------------------------------------------------------------------------
__global__ __launch_bounds__(256) void gat_scores(const float* __restrict__ h,
                                                  const float* __restrict__ u1,
                                                  const float* __restrict__ u2,
                                                  float* __restrict__ s1,
                                                  float* __restrict__ s2) {
    int gtid = blockIdx.x * blockDim.x + threadIdx.x;
    int row  = gtid >> 6;
    int lane = gtid & 63;
    if (row >= N) return;
    const float* hr = h + (size_t)row * FIN;
    float a1 = 0.f, a2 = 0.f;
    #pragma unroll
    for (int it = 0; it < FIN / 256; ++it) {   // 2 iters
        int base = it * 256 + lane * 4;
        fv4 hv  = *(const fv4*)(hr + base);
        fv4 v1  = *(const fv4*)(u1 + base);
        fv4 v2  = *(const fv4*)(u2 + base);
        a1 += hv.x * v1.x + hv.y * v1.y + hv.z * v1.z + hv.w * v1.w;
        a2 += hv.x * v2.x + hv.y * v2.y + hv.z * v2.z + hv.w * v2.w;
    }
    #pragma unroll
    for (int off = 32; off > 0; off >>= 1) {
        a1 += __shfl_xor(a1, off);
        a2 += __shfl_xor(a2, off);
    }
    if (lane == 0) {
        s1[row] = a1;
        s2[row] = a2;
    }
}

// ---------------------------------------------------------------------------
// Kernel C: fused masked-leakyrelu-softmax, 4 rows per block.
// No max shift (softmax shift-invariant; exp args bounded ~|20| << 88).
// s2 fragment (16 floats/thread, same indices for every row) hoisted into
// registers ONCE and reused across the 4 rows. adj: NT load (268 MB streamed
// once); out: NT store (268 MB). LDS reduce slots double-buffered so one
// barrier per row suffices.
// ---------------------------------------------------------------------------
__global__ __launch_bounds__(512) void gat_attn_row(const int* __restrict__ adj,
                                                    const float* __restrict__ s1,
                                                    const float* __restrict__ s2,
                                                    float* __restrict__ out) {
    const int t    = threadIdx.x;
    const int row0 = blockIdx.x * ROWS_PER_BLOCK;

    // cached s2 loads first — keep them ahead of the NT HBM stream
    fv4 sv[4];
    #pragma unroll
    for (int c = 0; c < 4; ++c)
        sv[c] = ((const fv4*)s2)[c * 512 + t];

    __shared__ float red[2][8];
    const int wid = t >> 6;

    #pragma unroll
    for (int r = 0; r < ROWS_PER_BLOCK; ++r) {
        const int row = row0 + r;
        const float s1i = s1[row];

        // issue all 4 NT adj loads as one clause (max MLP)
        const iv4* arow = (const iv4*)(adj + (size_t)row * N);
        iv4 av[4];
        #pragma unroll
        for (int c = 0; c < 4; ++c)
            av[c] = __builtin_nontemporal_load(arow + c * 512 + t);

        float p[16];
        float lsum = 0.f;
        #pragma unroll
        for (int c = 0; c < 4; ++c) {
            float e0 = s1i + sv[c].x; e0 = (e0 > 0.f) ? e0 : ALPHA * e0;
            float e1 = s1i + sv[c].y; e1 = (e1 > 0.f) ? e1 : ALPHA * e1;
            float e2 = s1i + sv[c].z; e2 = (e2 > 0.f) ? e2 : ALPHA * e2;
            float e3 = s1i + sv[c].w; e3 = (e3 > 0.f) ? e3 : ALPHA * e3;
            float p0 = (av[c].x > 0) ? __expf(e0) : 0.f;
            float p1 = (av[c].y > 0) ? __expf(e1) : 0.f;
            float p2 = (av[c].z > 0) ? __expf(e2) : 0.f;
            float p3 = (av[c].w > 0) ? __expf(e3) : 0.f;
            p[c * 4 + 0] = p0;
            p[c * 4 + 1] = p1;
            p[c * 4 + 2] = p2;
            p[c * 4 + 3] = p3;
            lsum += (p0 + p1) + (p2 + p3);
        }

        // block-wide sum: wave shuffle reduce, then 8 wave partials via LDS
        #pragma unroll
        for (int off = 32; off > 0; off >>= 1)
            lsum += __shfl_xor(lsum, off);
        float* rs = red[r & 1];
        if ((t & 63) == 0) rs[wid] = lsum;
        __syncthreads();
        float bsum = ((rs[0] + rs[1]) + (rs[2] + rs[3])) +
                     ((rs[4] + rs[5]) + (rs[6] + rs[7]));
        float inv = 1.0f / bsum;

        // single coalesced nontemporal fv4 write pass
        fv4* orow = (fv4*)(out + (size_t)row * N);
        #pragma unroll
        for (int c = 0; c < 4; ++c) {
            fv4 o;
            o.x = p[c * 4 + 0] * inv;
            o.y = p[c * 4 + 1] * inv;
            o.z = p[c * 4 + 2] * inv;
            o.w = p[c * 4 + 3] * inv;
            __builtin_nontemporal_store(o, orow + c * 512 + t);
        }
    }
}

// ---------------------------------------------------------------------------
extern "C" void kernel_launch(void* const* d_in, const int* in_sizes, int n_in,
                              void* d_out, int out_size, void* d_ws, size_t ws_size,
                              hipStream_t stream) {
    const float* h   = (const float*)d_in[0];
    const int*   adj = (const int*)d_in[1];
    const float* W   = (const float*)d_in[2];
    const float* a   = (const float*)d_in[3];
    float*       out = (float*)d_out;

    // workspace layout (floats): u1[512] | u2[512] | s1[8192] | s2[8192]
    float* u1 = (float*)d_ws;
    float* u2 = u1 + FIN;
    float* s1 = u2 + FIN;
    float* s2 = s1 + N;

    gat_compute_u<<<(FIN * 64) / 256, 256, 0, stream>>>(W, a, u1, u2);
    gat_scores<<<(N * 64) / 256, 256, 0, stream>>>(h, u1, u2, s1, s2);
    gat_attn_row<<<N / ROWS_PER_BLOCK, 512, 0, stream>>>(adj, s1, s2, out);
}

// Round 6
// 100.423 us; speedup vs baseline: 1.1156x; 1.1156x over previous
//
#include <hip/hip_runtime.h>

#define N 8192
#define FIN 512
#define FOUT 256
#define ALPHA 0.2f

// native clang vector types — required by __builtin_nontemporal_load/store
typedef int   iv4 __attribute__((ext_vector_type(4)));
typedef float fv4 __attribute__((ext_vector_type(4)));

// ---------------------------------------------------------------------------
// Kernel A: u1 = W @ a[:256], u2 = W @ a[256:]   (512-length vectors)
// One wave per output k: 64 lanes x fv4 = the full contiguous 256-float row
// of W (coalesced), dot with a, shuffle-reduce. 512 waves total.
// ---------------------------------------------------------------------------
__global__ __launch_bounds__(256) void gat_compute_u(const float* __restrict__ W,
                                                     const float* __restrict__ a,
                                                     float* __restrict__ u1,
                                                     float* __restrict__ u2) {
    int gtid = blockIdx.x * blockDim.x + threadIdx.x;
    int k    = gtid >> 6;
    int lane = gtid & 63;
    if (k >= FIN) return;
    fv4 wv  = *(const fv4*)(W + (size_t)k * FOUT + lane * 4);
    fv4 a1v = *(const fv4*)(a + lane * 4);
    fv4 a2v = *(const fv4*)(a + FOUT + lane * 4);
    float acc1 = wv.x * a1v.x + wv.y * a1v.y + wv.z * a1v.z + wv.w * a1v.w;
    float acc2 = wv.x * a2v.x + wv.y * a2v.y + wv.z * a2v.z + wv.w * a2v.w;
    #pragma unroll
    for (int off = 32; off > 0; off >>= 1) {
        acc1 += __shfl_xor(acc1, off);
        acc2 += __shfl_xor(acc2, off);
    }
    if (lane == 0) {
        u1[k] = acc1;
        u2[k] = acc2;
    }
}

// ---------------------------------------------------------------------------
// Kernel B: s1[i] = dot(h[i,:], u1), s2[i] = dot(h[i,:], u2)
// One wave per row; fv4 loads; reads h once (16 MB). 512-thread blocks.
// ---------------------------------------------------------------------------
__global__ __launch_bounds__(512) void gat_scores(const float* __restrict__ h,
                                                  const float* __restrict__ u1,
                                                  const float* __restrict__ u2,
                                                  float* __restrict__ s1,
                                                  float* __restrict__ s2) {
    int gtid = blockIdx.x * blockDim.x + threadIdx.x;
    int row  = gtid >> 6;
    int lane = gtid & 63;
    if (row >= N) return;
    const float* hr = h + (size_t)row * FIN;
    float a1 = 0.f, a2 = 0.f;
    #pragma unroll
    for (int it = 0; it < FIN / 256; ++it) {   // 2 iters
        int base = it * 256 + lane * 4;
        fv4 hv  = *(const fv4*)(hr + base);
        fv4 v1  = *(const fv4*)(u1 + base);
        fv4 v2  = *(const fv4*)(u2 + base);
        a1 += hv.x * v1.x + hv.y * v1.y + hv.z * v1.z + hv.w * v1.w;
        a2 += hv.x * v2.x + hv.y * v2.y + hv.z * v2.z + hv.w * v2.w;
    }
    #pragma unroll
    for (int off = 32; off > 0; off >>= 1) {
        a1 += __shfl_xor(a1, off);
        a2 += __shfl_xor(a2, off);
    }
    if (lane == 0) {
        s1[row] = a1;
        s2[row] = a2;
    }
}

// ---------------------------------------------------------------------------
// Kernel C: fused masked-leakyrelu-softmax, ONE row per block (R4 structure —
// independent blocks give free inter-block overlap across the single barrier;
// R5's multi-row variant serialized this and regressed 11%).
// No max shift (softmax shift-invariant; exp args bounded ~|20| << 88).
// NT adj loads issued FIRST (long-latency HBM stream gets the head start),
// then cached s2 loads (L2 hits fill in behind). out: NT store.
// ---------------------------------------------------------------------------
__global__ __launch_bounds__(512) void gat_attn_row(const int* __restrict__ adj,
                                                    const float* __restrict__ s1,
                                                    const float* __restrict__ s2,
                                                    float* __restrict__ out) {
    const int row = blockIdx.x;
    const int t   = threadIdx.x;

    // long-latency NT adj loads first
    const iv4* arow = (const iv4*)(adj + (size_t)row * N);
    iv4 av[4];
    #pragma unroll
    for (int c = 0; c < 4; ++c)
        av[c] = __builtin_nontemporal_load(arow + c * 512 + t);

    // cached loads behind them
    const fv4* s2v = (const fv4*)s2;
    fv4 sv[4];
    #pragma unroll
    for (int c = 0; c < 4; ++c)
        sv[c] = s2v[c * 512 + t];

    const float s1i = s1[row];

    float p[16];
    float lsum = 0.f;
    #pragma unroll
    for (int c = 0; c < 4; ++c) {
        float e0 = s1i + sv[c].x; e0 = (e0 > 0.f) ? e0 : ALPHA * e0;
        float e1 = s1i + sv[c].y; e1 = (e1 > 0.f) ? e1 : ALPHA * e1;
        float e2 = s1i + sv[c].z; e2 = (e2 > 0.f) ? e2 : ALPHA * e2;
        float e3 = s1i + sv[c].w; e3 = (e3 > 0.f) ? e3 : ALPHA * e3;
        float p0 = (av[c].x > 0) ? __expf(e0) : 0.f;
        float p1 = (av[c].y > 0) ? __expf(e1) : 0.f;
        float p2 = (av[c].z > 0) ? __expf(e2) : 0.f;
        float p3 = (av[c].w > 0) ? __expf(e3) : 0.f;
        p[c * 4 + 0] = p0;
        p[c * 4 + 1] = p1;
        p[c * 4 + 2] = p2;
        p[c * 4 + 3] = p3;
        lsum += (p0 + p1) + (p2 + p3);
    }

    // block-wide sum: wave shuffle reduce, then 8 wave partials via LDS
    #pragma unroll
    for (int off = 32; off > 0; off >>= 1)
        lsum += __shfl_xor(lsum, off);
    __shared__ float red[8];
    int wid = t >> 6;
    if ((t & 63) == 0) red[wid] = lsum;
    __syncthreads();
    float bsum = ((red[0] + red[1]) + (red[2] + red[3])) +
                 ((red[4] + red[5]) + (red[6] + red[7]));
    float inv = 1.0f / bsum;

    // single coalesced nontemporal fv4 write pass
    fv4* orow = (fv4*)(out + (size_t)row * N);
    #pragma unroll
    for (int c = 0; c < 4; ++c) {
        fv4 o;
        o.x = p[c * 4 + 0] * inv;
        o.y = p[c * 4 + 1] * inv;
        o.z = p[c * 4 + 2] * inv;
        o.w = p[c * 4 + 3] * inv;
        __builtin_nontemporal_store(o, orow + c * 512 + t);
    }
}

// ---------------------------------------------------------------------------
extern "C" void kernel_launch(void* const* d_in, const int* in_sizes, int n_in,
                              void* d_out, int out_size, void* d_ws, size_t ws_size,
                              hipStream_t stream) {
    const float* h   = (const float*)d_in[0];
    const int*   adj = (const int*)d_in[1];
    const float* W   = (const float*)d_in[2];
    const float* a   = (const float*)d_in[3];
    float*       out = (float*)d_out;

    // workspace layout (floats): u1[512] | u2[512] | s1[8192] | s2[8192]
    float* u1 = (float*)d_ws;
    float* u2 = u1 + FIN;
    float* s1 = u2 + FIN;
    float* s2 = s1 + N;

    gat_compute_u<<<(FIN * 64) / 256, 256, 0, stream>>>(W, a, u1, u2);
    gat_scores<<<(N * 64) / 512, 512, 0, stream>>>(h, u1, u2, s1, s2);
    gat_attn_row<<<N, 512, 0, stream>>>(adj, s1, s2, out);
}